// Round 1
// baseline (1522.733 us; speedup 1.0000x reference)
//
#include <hip/hip_runtime.h>
#include <hip/hip_bf16.h>
#include <cstdint>
#include <cstddef>

#define Bsz 16384
#define Hsz 512
#define OUTsz 4
#define FFsz 2048
#define HORsz 5

using bf16_t = __hip_bfloat16;
typedef __bf16 bf16x8 __attribute__((ext_vector_type(8)));
typedef float f32x4 __attribute__((ext_vector_type(4)));

__device__ __forceinline__ void gld_lds16(const void* g, void* l) {
  __builtin_amdgcn_global_load_lds((__attribute__((address_space(1))) void*)g,
                                   (__attribute__((address_space(3))) void*)l,
                                   16, 0, 0);
}

__device__ __forceinline__ float sigm(float x) {
  return 1.f / (1.f + __expf(-x));
}
__device__ __forceinline__ float tanh_fast(float x) {
  x = fminf(fmaxf(x, -20.f), 20.f);
  float e = __expf(2.f * x);
  return (e - 1.f) / (e + 1.f);
}

// NT GEMM: C[M,N] = A[M,K] @ Bw[N,K]^T (+bias)
// MODE 0: Cf = acc + bias (fp32)
// MODE 1: Cb = bf16(relu(acc + bias))
// MODE 2: Cb = bf16(acc + bias); Cb2 = bf16(relu(acc + bias))
template <int MODE>
__global__ void __launch_bounds__(256, 2) gemm_nt(
    const bf16_t* __restrict__ A, int lda,
    const bf16_t* __restrict__ Bw, int K,
    const float* __restrict__ bias,
    float* __restrict__ Cf, bf16_t* __restrict__ Cb, bf16_t* __restrict__ Cb2,
    int ldc)
{
  __shared__ bf16_t sA[4096];   // 128 rows x 32 k, row-major
  __shared__ bf16_t sB[4096];
  const int t = threadIdx.x;
  const int w = t >> 6;
  const int lane = t & 63;
  const int m0 = blockIdx.x * 128;
  const int n0 = blockIdx.y * 128;
  const int wm = (w >> 1) * 64;
  const int wn = (w & 1) * 64;
  const int srow = t >> 2;          // staging row 0..63
  const int scol = (t & 3) * 8;     // staging k col (elements)
  const int k8 = (lane >> 4) * 8;   // fragment k offset
  const int lr = lane & 15;

  const bf16_t* Ag0 = A + (size_t)(m0 + srow) * lda + scol;
  const bf16_t* Ag1 = A + (size_t)(m0 + 64 + srow) * lda + scol;
  const bf16_t* Bg0 = Bw + (size_t)(n0 + srow) * K + scol;
  const bf16_t* Bg1 = Bw + (size_t)(n0 + 64 + srow) * K + scol;
  char* lA = (char*)sA + w * 1024;  // wave-uniform LDS base; HW adds lane*16
  char* lB = (char*)sB + w * 1024;

  f32x4 acc[4][4];
  const f32x4 zero = {0.f, 0.f, 0.f, 0.f};
  #pragma unroll
  for (int i = 0; i < 4; ++i)
    #pragma unroll
    for (int j = 0; j < 4; ++j)
      acc[i][j] = zero;

  for (int k0 = 0; k0 < K; k0 += 32) {
    __syncthreads();
    gld_lds16(Ag0 + k0, lA);
    gld_lds16(Ag1 + k0, lA + 4096);
    gld_lds16(Bg0 + k0, lB);
    gld_lds16(Bg1 + k0, lB + 4096);
    __syncthreads();
    bf16x8 af[4], bfm[4];
    #pragma unroll
    for (int i = 0; i < 4; ++i) {
      af[i]  = *(const bf16x8*)(sA + (wm + i * 16 + lr) * 32 + k8);
      bfm[i] = *(const bf16x8*)(sB + (wn + i * 16 + lr) * 32 + k8);
    }
    #pragma unroll
    for (int i = 0; i < 4; ++i)
      #pragma unroll
      for (int j = 0; j < 4; ++j)
        acc[i][j] = __builtin_amdgcn_mfma_f32_16x16x32_bf16(af[i], bfm[j], acc[i][j], 0, 0, 0);
  }

  const int rbase = (lane >> 4) * 4;
  #pragma unroll
  for (int i = 0; i < 4; ++i) {
    const int row0 = m0 + wm + i * 16 + rbase;
    #pragma unroll
    for (int j = 0; j < 4; ++j) {
      const int col = n0 + wn + j * 16 + lr;
      const float bv = bias[col];
      #pragma unroll
      for (int r = 0; r < 4; ++r) {
        const float v = acc[i][j][r] + bv;
        const size_t off = (size_t)(row0 + r) * ldc + col;
        if (MODE == 0) {
          Cf[off] = v;
        } else if (MODE == 1) {
          Cb[off] = __float2bfloat16(fmaxf(v, 0.f));
        } else {
          Cb[off] = __float2bfloat16(v);
          Cb2[off] = __float2bfloat16(fmaxf(v, 0.f));
        }
      }
    }
  }
}

// GRU elementwise gate: h' = (1-z)*n + z*h, gi computed inline (4-wide input)
__global__ void __launch_bounds__(256) gru_gate(
    const float* __restrict__ gh,       // [B,1536], b_hh already added
    const float* __restrict__ x, int ldx, // fp32, cols 0..3 used
    const float* __restrict__ w_ih,     // [1536,4]
    const float* __restrict__ b_ih,     // [1536]
    const bf16_t* __restrict__ hprev, int ldh,
    bf16_t* __restrict__ hout, int ldo)
{
  const int idx = blockIdx.x * 256 + threadIdx.x;
  const int b = idx >> 9;
  const int j = idx & 511;
  const float* xb = x + (size_t)b * ldx;
  const float x0 = xb[0], x1 = xb[1], x2 = xb[2], x3 = xb[3];
  const float* wr = w_ih + j * 4;
  const float* wz = w_ih + (j + 512) * 4;
  const float* wn = w_ih + (j + 1024) * 4;
  const float gir = b_ih[j]        + x0*wr[0] + x1*wr[1] + x2*wr[2] + x3*wr[3];
  const float giz = b_ih[j + 512]  + x0*wz[0] + x1*wz[1] + x2*wz[2] + x3*wz[3];
  const float gin = b_ih[j + 1024] + x0*wn[0] + x1*wn[1] + x2*wn[2] + x3*wn[3];
  const float* ghb = gh + (size_t)b * 1536;
  const float r = sigm(gir + ghb[j]);
  const float z = sigm(giz + ghb[j + 512]);
  const float n = tanh_fast(gin + r * ghb[j + 1024]);
  const float h = __bfloat162float(hprev[(size_t)b * ldh + j]);
  hout[(size_t)b * ldo + j] = __float2bfloat16((1.f - z) * n + z * h);
}

// mlp2: d = act[b,:]@w2^T + b2; xy += d; out[b,i,:] = xy. One wave per row.
__global__ void __launch_bounds__(256) mlp2_kernel(
    const bf16_t* __restrict__ act,   // [B,2048]
    const float* __restrict__ w2,     // [4,2048]
    const float* __restrict__ b2,
    float* __restrict__ xy,           // [B,4]
    float* __restrict__ out,          // [B,5,4]
    int istep)
{
  const int wv = threadIdx.x >> 6;
  const int lane = threadIdx.x & 63;
  const int b = blockIdx.x * 4 + wv;
  const bf16x8* ar8 = (const bf16x8*)(act + (size_t)b * 2048 + lane * 32);
  const int kbase = lane * 32;
  float s0 = 0.f, s1 = 0.f, s2 = 0.f, s3 = 0.f;
  #pragma unroll
  for (int q = 0; q < 4; ++q) {
    bf16x8 v = ar8[q];
    #pragma unroll
    for (int jj = 0; jj < 8; ++jj) {
      const float a = (float)v[jj];
      const int k = kbase + q * 8 + jj;
      s0 += a * w2[k];
      s1 += a * w2[2048 + k];
      s2 += a * w2[4096 + k];
      s3 += a * w2[6144 + k];
    }
  }
  #pragma unroll
  for (int off = 32; off > 0; off >>= 1) {
    s0 += __shfl_down(s0, off);
    s1 += __shfl_down(s1, off);
    s2 += __shfl_down(s2, off);
    s3 += __shfl_down(s3, off);
  }
  if (lane == 0) {
    float* xyb = xy + (size_t)b * 4;
    const float o0 = xyb[0] + s0 + b2[0];
    const float o1 = xyb[1] + s1 + b2[1];
    const float o2 = xyb[2] + s2 + b2[2];
    const float o3 = xyb[3] + s3 + b2[3];
    xyb[0] = o0; xyb[1] = o1; xyb[2] = o2; xyb[3] = o3;
    float* ob = out + (size_t)b * (HORsz * OUTsz) + istep * 4;
    ob[0] = o0; ob[1] = o1; ob[2] = o2; ob[3] = o3;
  }
}

__global__ void __launch_bounds__(256) f2b(const float* __restrict__ x,
                                           bf16_t* __restrict__ y, int n) {
  const int i = blockIdx.x * 256 + threadIdx.x;
  if (i < n) y[i] = __float2bfloat16(x[i]);
}

extern "C" void kernel_launch(void* const* d_in, const int* in_sizes, int n_in,
                              void* d_out, int out_size, void* d_ws, size_t ws_size,
                              hipStream_t stream)
{
  const float* pv   = (const float*)d_in[0];
  const float* ptf  = (const float*)d_in[1];
  const float* w_ih = (const float*)d_in[2];
  const float* w_hh = (const float*)d_in[3];
  const float* b_ih = (const float*)d_in[4];
  const float* b_hh = (const float*)d_in[5];
  const float* w_fc = (const float*)d_in[6];
  const float* b_fc = (const float*)d_in[7];
  const float* w1   = (const float*)d_in[8];
  const float* b1   = (const float*)d_in[9];
  const float* w2   = (const float*)d_in[10];
  const float* b2   = (const float*)d_in[11];
  float* out = (float*)d_out;

  char* p = (char*)d_ws;
  auto carve = [&](size_t bytes) {
    char* r = p;
    p += (bytes + 255) & ~(size_t)255;
    return r;
  };
  float*  gh    = (float*)carve((size_t)Bsz * 1536 * 4);   // 96 MB
  bf16_t* act   = (bf16_t*)gh;                             // alias, disjoint lifetime
  bf16_t* hcat  = (bf16_t*)carve((size_t)Bsz * 1024 * 2);  // [h1|h2]
  bf16_t* hx    = (bf16_t*)carve((size_t)Bsz * 512 * 2);
  bf16_t* hxr   = (bf16_t*)carve((size_t)Bsz * 512 * 2);
  float*  xy    = (float*)carve((size_t)Bsz * 4 * 4);
  bf16_t* whh_b = (bf16_t*)carve((size_t)1536 * 512 * 2);
  bf16_t* wfc_b = (bf16_t*)carve((size_t)512 * 1024 * 2);
  bf16_t* w1_b  = (bf16_t*)carve((size_t)2048 * 512 * 2);

  f2b<<<1536 * 512 / 256, 256, 0, stream>>>(w_hh, whh_b, 1536 * 512);
  f2b<<<512 * 1024 / 256, 256, 0, stream>>>(w_fc, wfc_b, 512 * 1024);
  f2b<<<2048 * 512 / 256, 256, 0, stream>>>(w1, w1_b, 2048 * 512);
  f2b<<<Bsz * 512 / 256, 256, 0, stream>>>(ptf, hx, Bsz * 512);
  hipMemsetAsync(xy, 0, (size_t)Bsz * 4 * 4, stream);

  for (int i = 0; i < HORsz; ++i) {
    // h1 = GRUCell(xy, hx)
    gemm_nt<0><<<dim3(Bsz / 128, 1536 / 128), 256, 0, stream>>>(
        hx, 512, whh_b, 512, b_hh, gh, nullptr, nullptr, 1536);
    gru_gate<<<Bsz * 512 / 256, 256, 0, stream>>>(
        gh, xy, 4, w_ih, b_ih, hx, 512, hcat, 1024);
    // h2 = GRUCell(pv[:, i], h1)
    gemm_nt<0><<<dim3(Bsz / 128, 1536 / 128), 256, 0, stream>>>(
        hcat, 1024, whh_b, 512, b_hh, gh, nullptr, nullptr, 1536);
    gru_gate<<<Bsz * 512 / 256, 256, 0, stream>>>(
        gh, pv + i * 4, HORsz * OUTsz, w_ih, b_ih, hcat, 1024, hcat + 512, 1024);
    // hx = hcat @ w_fc^T + b_fc (bf16); hxr = relu(hx)
    gemm_nt<2><<<dim3(Bsz / 128, 512 / 128), 256, 0, stream>>>(
        hcat, 1024, wfc_b, 1024, b_fc, nullptr, hx, hxr, 512);
    // act = relu(hxr @ w1^T + b1)
    gemm_nt<1><<<dim3(Bsz / 128, 2048 / 128), 256, 0, stream>>>(
        hxr, 512, w1_b, 512, b1, nullptr, act, nullptr, 2048);
    // xy += act @ w2^T + b2; out[:, i, :] = xy
    mlp2_kernel<<<Bsz / 4, 256, 0, stream>>>(act, w2, b2, xy, out, i);
  }
}

// Round 2
// 1287.508 us; speedup vs baseline: 1.1827x; 1.1827x over previous
//
#include <hip/hip_runtime.h>
#include <hip/hip_bf16.h>
#include <cstdint>
#include <cstddef>

#define Bsz 16384
#define Hsz 512
#define OUTsz 4
#define FFsz 2048
#define HORsz 5

using bf16_t = __hip_bfloat16;
typedef __bf16 bf16x8 __attribute__((ext_vector_type(8)));
typedef __bf16 bf16x4 __attribute__((ext_vector_type(4)));
typedef float f32x4 __attribute__((ext_vector_type(4)));

__device__ __forceinline__ void gld_lds16(const void* g, void* l) {
  __builtin_amdgcn_global_load_lds((__attribute__((address_space(1))) void*)g,
                                   (__attribute__((address_space(3))) void*)l,
                                   16, 0, 0);
}

__device__ __forceinline__ float sigm(float x) {
  return 1.f / (1.f + __expf(-x));
}
__device__ __forceinline__ float tanh_fast(float x) {
  x = fminf(fmaxf(x, -20.f), 20.f);
  float e = __expf(2.f * x);
  return (e - 1.f) / (e + 1.f);
}

// NT GEMM: C[M,N] = A[M,K] @ Bw[N,K]^T (+bias)
// MODE 0: Cb = bf16(acc + bias)
// MODE 1: Cb = bf16(relu(acc + bias))
// MODE 2: Cb = bf16(acc + bias); Cb2 = bf16(relu(acc + bias))
template <int MODE>
__global__ void __launch_bounds__(256, 2) gemm_nt(
    const bf16_t* __restrict__ A, int lda,
    const bf16_t* __restrict__ Bw, int K,
    const float* __restrict__ bias,
    bf16_t* __restrict__ Cb, bf16_t* __restrict__ Cb2,
    int ldc)
{
  __shared__ bf16_t sA[4096];   // 128 rows x 32 k, row-major
  __shared__ bf16_t sB[4096];
  const int t = threadIdx.x;
  const int w = t >> 6;
  const int lane = t & 63;
  const int m0 = blockIdx.x * 128;
  const int n0 = blockIdx.y * 128;
  const int wm = (w >> 1) * 64;
  const int wn = (w & 1) * 64;
  const int srow = t >> 2;          // staging row 0..63
  const int scol = (t & 3) * 8;     // staging k col (elements)
  const int k8 = (lane >> 4) * 8;   // fragment k offset
  const int lr = lane & 15;

  const bf16_t* Ag0 = A + (size_t)(m0 + srow) * lda + scol;
  const bf16_t* Ag1 = A + (size_t)(m0 + 64 + srow) * lda + scol;
  const bf16_t* Bg0 = Bw + (size_t)(n0 + srow) * K + scol;
  const bf16_t* Bg1 = Bw + (size_t)(n0 + 64 + srow) * K + scol;
  char* lA = (char*)sA + w * 1024;  // wave-uniform LDS base; HW adds lane*16
  char* lB = (char*)sB + w * 1024;

  f32x4 acc[4][4];
  const f32x4 zero = {0.f, 0.f, 0.f, 0.f};
  #pragma unroll
  for (int i = 0; i < 4; ++i)
    #pragma unroll
    for (int j = 0; j < 4; ++j)
      acc[i][j] = zero;

  for (int k0 = 0; k0 < K; k0 += 32) {
    __syncthreads();
    gld_lds16(Ag0 + k0, lA);
    gld_lds16(Ag1 + k0, lA + 4096);
    gld_lds16(Bg0 + k0, lB);
    gld_lds16(Bg1 + k0, lB + 4096);
    __syncthreads();
    bf16x8 af[4], bfm[4];
    #pragma unroll
    for (int i = 0; i < 4; ++i) {
      af[i]  = *(const bf16x8*)(sA + (wm + i * 16 + lr) * 32 + k8);
      bfm[i] = *(const bf16x8*)(sB + (wn + i * 16 + lr) * 32 + k8);
    }
    #pragma unroll
    for (int i = 0; i < 4; ++i)
      #pragma unroll
      for (int j = 0; j < 4; ++j)
        acc[i][j] = __builtin_amdgcn_mfma_f32_16x16x32_bf16(af[i], bfm[j], acc[i][j], 0, 0, 0);
  }

  const int rbase = (lane >> 4) * 4;
  #pragma unroll
  for (int i = 0; i < 4; ++i) {
    const int row0 = m0 + wm + i * 16 + rbase;
    #pragma unroll
    for (int j = 0; j < 4; ++j) {
      const int col = n0 + wn + j * 16 + lr;
      const float bv = bias[col];
      #pragma unroll
      for (int r = 0; r < 4; ++r) {
        const float v = acc[i][j][r] + bv;
        const size_t off = (size_t)(row0 + r) * ldc + col;
        if (MODE == 0) {
          Cb[off] = __float2bfloat16(v);
        } else if (MODE == 1) {
          Cb[off] = __float2bfloat16(fmaxf(v, 0.f));
        } else {
          Cb[off] = __float2bfloat16(v);
          Cb2[off] = __float2bfloat16(fmaxf(v, 0.f));
        }
      }
    }
  }
}

// GRU elementwise gate: h' = (1-z)*n + z*h, gi computed inline (4-wide input)
// 4 channels per thread, vectorized bf16x4 loads/stores.
__global__ void __launch_bounds__(256) gru_gate(
    const bf16_t* __restrict__ gh,        // [B,1536] bf16, b_hh already added
    const float* __restrict__ x, int ldx, // fp32, cols 0..3 used
    const float* __restrict__ w_ih,       // [1536,4]
    const float* __restrict__ b_ih,       // [1536]
    const bf16_t* __restrict__ hprev, int ldh,
    bf16_t* __restrict__ hout, int ldo)
{
  const int idx = blockIdx.x * 256 + threadIdx.x;   // B*128 threads
  const int b = idx >> 7;
  const int j4 = (idx & 127) * 4;
  const float* xb = x + (size_t)b * ldx;
  const float x0 = xb[0], x1 = xb[1], x2 = xb[2], x3 = xb[3];
  const bf16_t* ghb = gh + (size_t)b * 1536;
  const bf16x4 gr = *(const bf16x4*)(ghb + j4);
  const bf16x4 gz = *(const bf16x4*)(ghb + 512 + j4);
  const bf16x4 gn = *(const bf16x4*)(ghb + 1024 + j4);
  const bf16x4 hp = *(const bf16x4*)(hprev + (size_t)b * ldh + j4);
  bf16x4 ho;
  #pragma unroll
  for (int c = 0; c < 4; ++c) {
    const int j = j4 + c;
    const float* wr = w_ih + j * 4;
    const float* wz = w_ih + (j + 512) * 4;
    const float* wn = w_ih + (j + 1024) * 4;
    const float gir = b_ih[j]        + x0*wr[0] + x1*wr[1] + x2*wr[2] + x3*wr[3];
    const float giz = b_ih[j + 512]  + x0*wz[0] + x1*wz[1] + x2*wz[2] + x3*wz[3];
    const float gin = b_ih[j + 1024] + x0*wn[0] + x1*wn[1] + x2*wn[2] + x3*wn[3];
    const float r = sigm(gir + (float)gr[c]);
    const float z = sigm(giz + (float)gz[c]);
    const float n = tanh_fast(gin + r * (float)gn[c]);
    ho[c] = (__bf16)((1.f - z) * n + z * (float)hp[c]);
  }
  *(bf16x4*)(hout + (size_t)b * ldo + j4) = ho;
}

// mlp2: d = act[b,:]@w2^T + b2; xy += d; out[b,i,:] = xy. One wave per row.
// Coalesced: lane reads act[b][q*512 + lane*8] (16B/lane, contiguous 1KB/instr).
__global__ void __launch_bounds__(256) mlp2_kernel(
    const bf16_t* __restrict__ act,   // [B,2048]
    const float* __restrict__ w2,     // [4,2048]
    const float* __restrict__ b2,
    float* __restrict__ xy,           // [B,4]
    float* __restrict__ out,          // [B,5,4]
    int istep)
{
  const int wv = threadIdx.x >> 6;
  const int lane = threadIdx.x & 63;
  const int b = blockIdx.x * 4 + wv;
  const bf16_t* ar = act + (size_t)b * 2048;
  float s0 = 0.f, s1 = 0.f, s2 = 0.f, s3 = 0.f;
  #pragma unroll
  for (int q = 0; q < 4; ++q) {
    const int k = q * 512 + lane * 8;
    const bf16x8 v = *(const bf16x8*)(ar + k);
    const float* w0 = w2 + k;
    const float* w1p = w2 + 2048 + k;
    const float* w2p = w2 + 4096 + k;
    const float* w3p = w2 + 6144 + k;
    #pragma unroll
    for (int jj = 0; jj < 8; ++jj) {
      const float a = (float)v[jj];
      s0 += a * w0[jj];
      s1 += a * w1p[jj];
      s2 += a * w2p[jj];
      s3 += a * w3p[jj];
    }
  }
  #pragma unroll
  for (int off = 32; off > 0; off >>= 1) {
    s0 += __shfl_down(s0, off);
    s1 += __shfl_down(s1, off);
    s2 += __shfl_down(s2, off);
    s3 += __shfl_down(s3, off);
  }
  if (lane == 0) {
    float* xyb = xy + (size_t)b * 4;
    const float o0 = xyb[0] + s0 + b2[0];
    const float o1 = xyb[1] + s1 + b2[1];
    const float o2 = xyb[2] + s2 + b2[2];
    const float o3 = xyb[3] + s3 + b2[3];
    xyb[0] = o0; xyb[1] = o1; xyb[2] = o2; xyb[3] = o3;
    float* ob = out + (size_t)b * (HORsz * OUTsz) + istep * 4;
    ob[0] = o0; ob[1] = o1; ob[2] = o2; ob[3] = o3;
  }
}

__global__ void __launch_bounds__(256) f2b(const float* __restrict__ x,
                                           bf16_t* __restrict__ y, int n) {
  const int i = blockIdx.x * 256 + threadIdx.x;
  if (i < n) y[i] = __float2bfloat16(x[i]);
}

extern "C" void kernel_launch(void* const* d_in, const int* in_sizes, int n_in,
                              void* d_out, int out_size, void* d_ws, size_t ws_size,
                              hipStream_t stream)
{
  const float* pv   = (const float*)d_in[0];
  const float* ptf  = (const float*)d_in[1];
  const float* w_ih = (const float*)d_in[2];
  const float* w_hh = (const float*)d_in[3];
  const float* b_ih = (const float*)d_in[4];
  const float* b_hh = (const float*)d_in[5];
  const float* w_fc = (const float*)d_in[6];
  const float* b_fc = (const float*)d_in[7];
  const float* w1   = (const float*)d_in[8];
  const float* b1   = (const float*)d_in[9];
  const float* w2   = (const float*)d_in[10];
  const float* b2   = (const float*)d_in[11];
  float* out = (float*)d_out;

  char* p = (char*)d_ws;
  auto carve = [&](size_t bytes) {
    char* r = p;
    p += (bytes + 255) & ~(size_t)255;
    return r;
  };
  // act [B,2048] bf16 (64MB) aliases gh [B,1536] bf16 (48MB) — disjoint lifetimes
  bf16_t* act   = (bf16_t*)carve((size_t)Bsz * 2048 * 2);
  bf16_t* gh    = act;
  bf16_t* hcat  = (bf16_t*)carve((size_t)Bsz * 1024 * 2);  // [h1|h2]
  bf16_t* hx    = (bf16_t*)carve((size_t)Bsz * 512 * 2);
  bf16_t* hxr   = (bf16_t*)carve((size_t)Bsz * 512 * 2);
  float*  xy    = (float*)carve((size_t)Bsz * 4 * 4);
  bf16_t* whh_b = (bf16_t*)carve((size_t)1536 * 512 * 2);
  bf16_t* wfc_b = (bf16_t*)carve((size_t)512 * 1024 * 2);
  bf16_t* w1_b  = (bf16_t*)carve((size_t)2048 * 512 * 2);

  f2b<<<1536 * 512 / 256, 256, 0, stream>>>(w_hh, whh_b, 1536 * 512);
  f2b<<<512 * 1024 / 256, 256, 0, stream>>>(w_fc, wfc_b, 512 * 1024);
  f2b<<<2048 * 512 / 256, 256, 0, stream>>>(w1, w1_b, 2048 * 512);
  f2b<<<Bsz * 512 / 256, 256, 0, stream>>>(ptf, hx, Bsz * 512);
  hipMemsetAsync(xy, 0, (size_t)Bsz * 4 * 4, stream);

  for (int i = 0; i < HORsz; ++i) {
    // h1 = GRUCell(xy, hx)
    gemm_nt<0><<<dim3(Bsz / 128, 1536 / 128), 256, 0, stream>>>(
        hx, 512, whh_b, 512, b_hh, gh, nullptr, 1536);
    gru_gate<<<Bsz * 128 / 256, 256, 0, stream>>>(
        gh, xy, 4, w_ih, b_ih, hx, 512, hcat, 1024);
    // h2 = GRUCell(pv[:, i], h1)
    gemm_nt<0><<<dim3(Bsz / 128, 1536 / 128), 256, 0, stream>>>(
        hcat, 1024, whh_b, 512, b_hh, gh, nullptr, 1536);
    gru_gate<<<Bsz * 128 / 256, 256, 0, stream>>>(
        gh, pv + i * 4, HORsz * OUTsz, w_ih, b_ih, hcat, 1024, hcat + 512, 1024);
    // hx = hcat @ w_fc^T + b_fc (bf16); hxr = relu(hx)
    gemm_nt<2><<<dim3(Bsz / 128, 512 / 128), 256, 0, stream>>>(
        hcat, 1024, wfc_b, 1024, b_fc, hx, hxr, 512);
    // act = relu(hxr @ w1^T + b1)
    gemm_nt<1><<<dim3(Bsz / 128, 2048 / 128), 256, 0, stream>>>(
        hxr, 512, w1_b, 512, b1, act, nullptr, 2048);
    // xy += act @ w2^T + b2; out[:, i, :] = xy
    mlp2_kernel<<<Bsz / 4, 256, 0, stream>>>(act, w2, b2, xy, out, i);
  }
}

// Round 3
// 1250.418 us; speedup vs baseline: 1.2178x; 1.0297x over previous
//
#include <hip/hip_runtime.h>
#include <hip/hip_bf16.h>
#include <cstdint>
#include <cstddef>

#define Bsz 16384
#define HORsz 5

using bf16_t = __hip_bfloat16;
typedef __bf16 bf16x8 __attribute__((ext_vector_type(8)));
typedef float f32x4 __attribute__((ext_vector_type(4)));

__device__ __forceinline__ float sigm(float x) { return 1.f / (1.f + __expf(-x)); }
__device__ __forceinline__ float tanh_fast(float x) {
  x = fminf(fmaxf(x, -20.f), 20.f);
  float e = __expf(2.f * x);
  return (e - 1.f) / (e + 1.f);
}

// Fragment layout (FL) for bf16 [R,C]: 1KB chunk = 16 rows x 32 cols, lane l <-> bytes [16l,16l+16).
// chunk = (row>>4)*ca + cofs + col>>5 ; within = (((col>>3)&3)*16 + (row&15))*16 + (col&7)*2
__device__ __forceinline__ size_t fl_off(int row, int col, int ca, int cofs) {
  return (size_t)((row >> 4) * ca + cofs + (col >> 5)) * 1024
       + (size_t)((((col >> 3) & 3) * 16 + (row & 15)) * 16 + (col & 7) * 2);
}

// fp32 row-major [R,C] -> bf16 FL. One thread per 8-col piece; dst stores fully coalesced.
__global__ void __launch_bounds__(256) pack_fl(const float* __restrict__ src,
                                               char* __restrict__ dst,
                                               int C, int cs, int npieces) {
  const int p = blockIdx.x * 256 + threadIdx.x;
  if (p >= npieces) return;
  const int chunk = p >> 6, wi = p & 63;
  const int colgrp = wi >> 4, r15 = wi & 15;
  const int rowgrp = chunk >> cs, kg = chunk & ((1 << cs) - 1);
  const int row = rowgrp * 16 + r15;
  const int col = kg * 32 + colgrp * 8;
  const float* s = src + (size_t)row * C + col;
  bf16x8 v;
  #pragma unroll
  for (int j = 0; j < 8; ++j) v[j] = (__bf16)s[j];
  *(bf16x8*)(dst + (size_t)p * 16) = v;
}

// Fused GRU cell: h' = (1-z)n + z*h for 512 channels, hprev == A (both FL).
// Block: 64 batch rows x 128 channels x 3 gates. No LDS, no barriers.
__global__ void __launch_bounds__(256, 2) gru_fused(
    const char* __restrict__ Afl, int ca,   // A = hprev, FL bf16, K=512 (col chunks 0..15)
    const char* __restrict__ Wfl,           // whh FL bf16 [1536,512] (16 chunks/rowgrp)
    const float* __restrict__ x, int ldx,   // fp32, 4 cols used
    const float* __restrict__ w_ih, const float* __restrict__ b_ih,
    const float* __restrict__ b_hh,
    char* __restrict__ Ofl, int co, int kofs)
{
  const int t = threadIdx.x, w = t >> 6, lane = t & 63;
  const int m0 = blockIdx.y * 64, rg0 = m0 >> 4;
  const int n0 = blockIdx.x * 128;
  const int wn = w * 32;
  const int nb = (n0 + wn) >> 4;

  f32x4 acc[3][4][2];
  const f32x4 zero = {0.f, 0.f, 0.f, 0.f};
  #pragma unroll
  for (int g = 0; g < 3; ++g)
    #pragma unroll
    for (int i = 0; i < 4; ++i)
      #pragma unroll
      for (int jt = 0; jt < 2; ++jt) acc[g][i][jt] = zero;

  const char* ap = Afl + (size_t)rg0 * ca * 1024 + lane * 16;
  const char* bp = Wfl + (size_t)nb * 16 * 1024 + lane * 16;
  // strides (bytes): gate g -> 512 rows = 32 rowgrps * 16KB = 524288; jt -> 16384; kg -> 1024

  #pragma unroll 4
  for (int kg = 0; kg < 16; ++kg) {
    bf16x8 af[4];
    #pragma unroll
    for (int i = 0; i < 4; ++i)
      af[i] = *(const bf16x8*)(ap + ((size_t)i * ca + kg) * 1024);
    #pragma unroll
    for (int g = 0; g < 3; ++g)
      #pragma unroll
      for (int jt = 0; jt < 2; ++jt) {
        const bf16x8 bv = *(const bf16x8*)(bp + (size_t)g * 524288 + jt * 16384 + (size_t)kg * 1024);
        #pragma unroll
        for (int i = 0; i < 4; ++i)
          acc[g][i][jt] = __builtin_amdgcn_mfma_f32_16x16x32_bf16(af[i], bv, acc[g][i][jt], 0, 0, 0);
      }
  }

  const int lr = lane & 15, q4 = (lane >> 4) * 4;
  #pragma unroll
  for (int jt = 0; jt < 2; ++jt) {
    const int c = n0 + wn + jt * 16 + lr;
    const float4 wr  = *(const float4*)(w_ih + (size_t)c * 4);
    const float4 wz  = *(const float4*)(w_ih + (size_t)(c + 512) * 4);
    const float4 wnn = *(const float4*)(w_ih + (size_t)(c + 1024) * 4);
    const float bir = b_ih[c], biz = b_ih[c + 512], bin = b_ih[c + 1024];
    const float bhr = b_hh[c], bhz = b_hh[c + 512], bhn = b_hh[c + 1024];
    #pragma unroll
    for (int i = 0; i < 4; ++i) {
      #pragma unroll
      for (int r4 = 0; r4 < 4; ++r4) {
        const int row = m0 + i * 16 + q4 + r4;
        const float4 xv = *(const float4*)(x + (size_t)row * ldx);
        const float gir = bir + xv.x * wr.x  + xv.y * wr.y  + xv.z * wr.z  + xv.w * wr.w;
        const float giz = biz + xv.x * wz.x  + xv.y * wz.y  + xv.z * wz.z  + xv.w * wz.w;
        const float gin = bin + xv.x * wnn.x + xv.y * wnn.y + xv.z * wnn.z + xv.w * wnn.w;
        const float rr = sigm(gir + acc[0][i][jt][r4] + bhr);
        const float zz = sigm(giz + acc[1][i][jt][r4] + bhz);
        const float nn = tanh_fast(gin + rr * (acc[2][i][jt][r4] + bhn));
        const float hp = (float)*(const __bf16*)(Afl + fl_off(row, c, ca, 0));
        *(__bf16*)(Ofl + fl_off(row, c, co, kofs)) = (__bf16)((1.f - zz) * nn + zz * hp);
      }
    }
  }
}

// LDS-free NT GEMM on FL inputs. MODE 1: Orow = bf16(relu(v)) row-major.
// MODE 2: O1 = bf16(v) FL ; O2 = bf16(relu(v)) FL.
template <int MODE>
__global__ void __launch_bounds__(256, 2) gemm_fl(
    const char* __restrict__ Afl,
    const char* __restrict__ Bfl,
    int nkg,                         // K>>5 (== chunks/rowgrp for both A and B)
    const float* __restrict__ bias,
    char* __restrict__ O1, char* __restrict__ O2, int co,
    bf16_t* __restrict__ Orow, int ldo)
{
  const int t = threadIdx.x, w = t >> 6, lane = t & 63;
  const int m0 = blockIdx.x * 128, n0 = blockIdx.y * 128;
  const int wm = (w >> 1) * 64, wn = (w & 1) * 64;

  f32x4 acc[4][4];
  const f32x4 zero = {0.f, 0.f, 0.f, 0.f};
  #pragma unroll
  for (int i = 0; i < 4; ++i)
    #pragma unroll
    for (int j = 0; j < 4; ++j) acc[i][j] = zero;

  const char* ap = Afl + (size_t)((m0 + wm) >> 4) * nkg * 1024 + lane * 16;
  const char* bp = Bfl + (size_t)((n0 + wn) >> 4) * nkg * 1024 + lane * 16;

  #pragma unroll 4
  for (int kg = 0; kg < nkg; ++kg) {
    bf16x8 af[4], bv[4];
    #pragma unroll
    for (int i = 0; i < 4; ++i)
      af[i] = *(const bf16x8*)(ap + ((size_t)i * nkg + kg) * 1024);
    #pragma unroll
    for (int j = 0; j < 4; ++j)
      bv[j] = *(const bf16x8*)(bp + ((size_t)j * nkg + kg) * 1024);
    #pragma unroll
    for (int i = 0; i < 4; ++i)
      #pragma unroll
      for (int j = 0; j < 4; ++j)
        acc[i][j] = __builtin_amdgcn_mfma_f32_16x16x32_bf16(af[i], bv[j], acc[i][j], 0, 0, 0);
  }

  const int lr = lane & 15, q4 = (lane >> 4) * 4;
  #pragma unroll
  for (int i = 0; i < 4; ++i) {
    #pragma unroll
    for (int j = 0; j < 4; ++j) {
      const int col = n0 + wn + j * 16 + lr;
      const float bvv = bias[col];
      #pragma unroll
      for (int r = 0; r < 4; ++r) {
        const int row = m0 + wm + i * 16 + q4 + r;
        const float v = acc[i][j][r] + bvv;
        if (MODE == 1) {
          Orow[(size_t)row * ldo + col] = __float2bfloat16(fmaxf(v, 0.f));
        } else {
          *(__bf16*)(O1 + fl_off(row, col, co, 0)) = (__bf16)v;
          *(__bf16*)(O2 + fl_off(row, col, co, 0)) = (__bf16)fmaxf(v, 0.f);
        }
      }
    }
  }
}

// mlp2: d = act[b,:]@w2^T + b2; xy += d; out[b,i,:] = xy. One wave per row (act row-major).
__global__ void __launch_bounds__(256) mlp2_kernel(
    const bf16_t* __restrict__ act,   // [B,2048]
    const float* __restrict__ w2,     // [4,2048]
    const float* __restrict__ b2,
    float* __restrict__ xy,           // [B,4]
    float* __restrict__ out,          // [B,5,4]
    int istep)
{
  const int wv = threadIdx.x >> 6;
  const int lane = threadIdx.x & 63;
  const int b = blockIdx.x * 4 + wv;
  const bf16_t* ar = act + (size_t)b * 2048;
  float s0 = 0.f, s1 = 0.f, s2 = 0.f, s3 = 0.f;
  #pragma unroll
  for (int q = 0; q < 4; ++q) {
    const int k = q * 512 + lane * 8;
    const bf16x8 v = *(const bf16x8*)(ar + k);
    const float* w0 = w2 + k;
    const float* w1p = w2 + 2048 + k;
    const float* w2p = w2 + 4096 + k;
    const float* w3p = w2 + 6144 + k;
    #pragma unroll
    for (int jj = 0; jj < 8; ++jj) {
      const float a = (float)v[jj];
      s0 += a * w0[jj];
      s1 += a * w1p[jj];
      s2 += a * w2p[jj];
      s3 += a * w3p[jj];
    }
  }
  #pragma unroll
  for (int off = 32; off > 0; off >>= 1) {
    s0 += __shfl_down(s0, off);
    s1 += __shfl_down(s1, off);
    s2 += __shfl_down(s2, off);
    s3 += __shfl_down(s3, off);
  }
  if (lane == 0) {
    float* xyb = xy + (size_t)b * 4;
    const float o0 = xyb[0] + s0 + b2[0];
    const float o1 = xyb[1] + s1 + b2[1];
    const float o2 = xyb[2] + s2 + b2[2];
    const float o3 = xyb[3] + s3 + b2[3];
    xyb[0] = o0; xyb[1] = o1; xyb[2] = o2; xyb[3] = o3;
    float* ob = out + (size_t)b * (HORsz * 4) + istep * 4;
    ob[0] = o0; ob[1] = o1; ob[2] = o2; ob[3] = o3;
  }
}

extern "C" void kernel_launch(void* const* d_in, const int* in_sizes, int n_in,
                              void* d_out, int out_size, void* d_ws, size_t ws_size,
                              hipStream_t stream)
{
  const float* pv   = (const float*)d_in[0];
  const float* ptf  = (const float*)d_in[1];
  const float* w_ih = (const float*)d_in[2];
  const float* w_hh = (const float*)d_in[3];
  const float* b_ih = (const float*)d_in[4];
  const float* b_hh = (const float*)d_in[5];
  const float* w_fc = (const float*)d_in[6];
  const float* b_fc = (const float*)d_in[7];
  const float* w1   = (const float*)d_in[8];
  const float* b1   = (const float*)d_in[9];
  const float* w2   = (const float*)d_in[10];
  const float* b2   = (const float*)d_in[11];
  float* out = (float*)d_out;

  char* p = (char*)d_ws;
  auto carve = [&](size_t bytes) {
    char* r = p;
    p += (bytes + 255) & ~(size_t)255;
    return r;
  };
  char*   hxF   = carve((size_t)Bsz * 512 * 2);    // FL, ca=16
  char*   hxrF  = carve((size_t)Bsz * 512 * 2);    // FL, ca=16
  char*   hcatF = carve((size_t)Bsz * 1024 * 2);   // FL, ca=32: h1 chunks 0..15, h2 chunks 16..31
  bf16_t* act   = (bf16_t*)carve((size_t)Bsz * 2048 * 2);  // row-major
  float*  xy    = (float*)carve((size_t)Bsz * 4 * 4);
  char*   whhF  = carve((size_t)1536 * 512 * 2);   // FL [1536,512], 16 chunks/rowgrp
  char*   wfcF  = carve((size_t)512 * 1024 * 2);   // FL [512,1024], 32 chunks/rowgrp
  char*   w1F   = carve((size_t)2048 * 512 * 2);   // FL [2048,512], 16 chunks/rowgrp

  pack_fl<<<(1536 * 512 / 8 + 255) / 256, 256, 0, stream>>>(w_hh, whhF, 512, 4, 1536 * 512 / 8);
  pack_fl<<<(512 * 1024 / 8 + 255) / 256, 256, 0, stream>>>(w_fc, wfcF, 1024, 5, 512 * 1024 / 8);
  pack_fl<<<(2048 * 512 / 8 + 255) / 256, 256, 0, stream>>>(w1, w1F, 512, 4, 2048 * 512 / 8);
  pack_fl<<<(Bsz * 512 / 8 + 255) / 256, 256, 0, stream>>>(ptf, hxF, 512, 4, Bsz * 512 / 8);
  hipMemsetAsync(xy, 0, (size_t)Bsz * 4 * 4, stream);

  for (int i = 0; i < HORsz; ++i) {
    // h1 = GRUCell(xy, hx)           -> hcat chunks 0..15
    gru_fused<<<dim3(4, Bsz / 64), 256, 0, stream>>>(
        hxF, 16, whhF, xy, 4, w_ih, b_ih, b_hh, hcatF, 32, 0);
    // h2 = GRUCell(pv[:,i], h1)      -> hcat chunks 16..31
    gru_fused<<<dim3(4, Bsz / 64), 256, 0, stream>>>(
        hcatF, 32, whhF, pv + i * 4, HORsz * 4, w_ih, b_ih, b_hh, hcatF, 32, 16);
    // hx = hcat @ w_fc^T + b_fc (FL); hxr = relu(hx) (FL)
    gemm_fl<2><<<dim3(Bsz / 128, 4), 256, 0, stream>>>(
        hcatF, wfcF, 32, b_fc, hxF, hxrF, 16, nullptr, 0);
    // act = relu(hxr @ w1^T + b1) (row-major)
    gemm_fl<1><<<dim3(Bsz / 128, 16), 256, 0, stream>>>(
        hxrF, w1F, 16, b1, nullptr, nullptr, 0, act, 2048);
    // xy += act @ w2^T + b2; out[:,i,:] = xy
    mlp2_kernel<<<Bsz / 4, 256, 0, stream>>>(act, w2, b2, xy, out, i);
  }
}

// Round 4
// 1132.579 us; speedup vs baseline: 1.3445x; 1.1040x over previous
//
#include <hip/hip_runtime.h>
#include <hip/hip_bf16.h>
#include <cstdint>
#include <cstddef>

#define Bsz 16384
#define HORsz 5

using bf16_t = __hip_bfloat16;
typedef __bf16 bf16x8 __attribute__((ext_vector_type(8)));
typedef float f32x4 __attribute__((ext_vector_type(4)));

__device__ __forceinline__ void gld_lds16(const void* g, void* l) {
  __builtin_amdgcn_global_load_lds((__attribute__((address_space(1))) void*)g,
                                   (__attribute__((address_space(3))) void*)l,
                                   16, 0, 0);
}

__device__ __forceinline__ float sigm(float x) { return 1.f / (1.f + __expf(-x)); }
__device__ __forceinline__ float tanh_fast(float x) {
  x = fminf(fmaxf(x, -20.f), 20.f);
  float e = __expf(2.f * x);
  return (e - 1.f) / (e + 1.f);
}

// Fragment layout (FL) bf16 [R,C]: 1KB chunk = 16 rows x 32 cols; lane l <-> bytes [16l,16l+16).
// chunk(rg,kg) at ((rg*ca)+cofs+kg)*1024 ; within: (((col>>3)&3)*16 + (row&15))*16 + (col&7)*2
__device__ __forceinline__ size_t fl_off(int row, int col, int ca, int cofs) {
  return (size_t)((row >> 4) * ca + cofs + (col >> 5)) * 1024
       + (size_t)((((col >> 3) & 3) * 16 + (row & 15)) * 16 + (col & 7) * 2);
}

// fp32 row-major [R,C] -> bf16 FL.
__global__ void __launch_bounds__(256) pack_fl(const float* __restrict__ src,
                                               char* __restrict__ dst,
                                               int C, int cs, int npieces) {
  const int p = blockIdx.x * 256 + threadIdx.x;
  if (p >= npieces) return;
  const int chunk = p >> 6, wi = p & 63;
  const int colgrp = wi >> 4, r15 = wi & 15;
  const int rowgrp = chunk >> cs, kg = chunk & ((1 << cs) - 1);
  const int row = rowgrp * 16 + r15;
  const int col = kg * 32 + colgrp * 8;
  const float* s = src + (size_t)row * C + col;
  bf16x8 v;
  #pragma unroll
  for (int j = 0; j < 8; ++j) v[j] = (__bf16)s[j];
  *(bf16x8*)(dst + (size_t)p * 16) = v;
}

// Fused GRU cell, LDS-staged. Block: 128 rows x 64 chans x 3 gates. K=512 (16 kg).
// Wave: 64 rows x 32 chans x 3 gates. LDS 20KB: A 8 chunks + B 12 chunks per kg.
__global__ void __launch_bounds__(256, 2) gru_fused2(
    const char* __restrict__ Afl, int ca,   // A = hprev FL, K chunks 0..15
    const char* __restrict__ Wfl,           // whh FL [1536,512], nkg=16
    const float* __restrict__ x, int ldx,   // fp32, 4 cols used
    const float* __restrict__ w_ih, const float* __restrict__ b_ih,
    const float* __restrict__ b_hh,
    char* __restrict__ Ofl, int co, int kofs)
{
  __shared__ char smem[20480];
  const int t = threadIdx.x, w = t >> 6, lane = t & 63;
  const int m0 = blockIdx.y * 128;
  const int n0 = blockIdx.x * 64;
  const int wm = (w >> 1) * 64, wc = (w & 1) * 32;

  // staging: 20 chunks/kg; wave w stages idx = w*5+s
  const char* gsrc[5];
  char* ldst[5];
  #pragma unroll
  for (int s = 0; s < 5; ++s) {
    const int idx = w * 5 + s;
    if (idx < 8) {
      gsrc[s] = Afl + (size_t)((m0 >> 4) + idx) * ca * 1024 + lane * 16;
    } else {
      const int c = idx - 8, g = c >> 2, cr = c & 3;
      gsrc[s] = Wfl + (size_t)(g * 32 + (n0 >> 4) + cr) * 16 * 1024 + lane * 16;
    }
    ldst[s] = smem + idx * 1024;
  }

  f32x4 acc[3][4][2];
  const f32x4 zero = {0.f, 0.f, 0.f, 0.f};
  #pragma unroll
  for (int g = 0; g < 3; ++g)
    #pragma unroll
    for (int i = 0; i < 4; ++i)
      #pragma unroll
      for (int jt = 0; jt < 2; ++jt) acc[g][i][jt] = zero;

  for (int kg = 0; kg < 16; ++kg) {
    __syncthreads();
    #pragma unroll
    for (int s = 0; s < 5; ++s)
      gld_lds16(gsrc[s] + (size_t)kg * 1024, ldst[s]);
    __syncthreads();
    bf16x8 af[4];
    #pragma unroll
    for (int i = 0; i < 4; ++i)
      af[i] = *(const bf16x8*)(smem + ((wm >> 4) + i) * 1024 + lane * 16);
    #pragma unroll
    for (int g = 0; g < 3; ++g)
      #pragma unroll
      for (int jt = 0; jt < 2; ++jt) {
        const bf16x8 bv = *(const bf16x8*)(smem + 8192 + (g * 4 + (w & 1) * 2 + jt) * 1024 + lane * 16);
        #pragma unroll
        for (int i = 0; i < 4; ++i)
          acc[g][i][jt] = __builtin_amdgcn_mfma_f32_16x16x32_bf16(af[i], bv, acc[g][i][jt], 0, 0, 0);
      }
  }

  const int lr = lane & 15, q4 = (lane >> 4) * 4;
  #pragma unroll
  for (int jt = 0; jt < 2; ++jt) {
    const int c = n0 + wc + jt * 16 + lr;
    const float4 wr  = *(const float4*)(w_ih + (size_t)c * 4);
    const float4 wz  = *(const float4*)(w_ih + (size_t)(c + 512) * 4);
    const float4 wnn = *(const float4*)(w_ih + (size_t)(c + 1024) * 4);
    const float bir = b_ih[c], biz = b_ih[c + 512], bin = b_ih[c + 1024];
    const float bhr = b_hh[c], bhz = b_hh[c + 512], bhn = b_hh[c + 1024];
    #pragma unroll
    for (int i = 0; i < 4; ++i) {
      #pragma unroll
      for (int r4 = 0; r4 < 4; ++r4) {
        const int row = m0 + wm + i * 16 + q4 + r4;
        const float4 xv = *(const float4*)(x + (size_t)row * ldx);
        const float gir = bir + xv.x * wr.x  + xv.y * wr.y  + xv.z * wr.z  + xv.w * wr.w;
        const float giz = biz + xv.x * wz.x  + xv.y * wz.y  + xv.z * wz.z  + xv.w * wz.w;
        const float gin = bin + xv.x * wnn.x + xv.y * wnn.y + xv.z * wnn.z + xv.w * wnn.w;
        const float rr = sigm(gir + acc[0][i][jt][r4] + bhr);
        const float zz = sigm(giz + acc[1][i][jt][r4] + bhz);
        const float nn = tanh_fast(gin + rr * (acc[2][i][jt][r4] + bhn));
        const float hp = (float)*(const __bf16*)(Afl + fl_off(row, c, ca, 0));
        *(__bf16*)(Ofl + fl_off(row, c, co, kofs)) = (__bf16)((1.f - zz) * nn + zz * hp);
      }
    }
  }
}

// Generic LDS-staged FL GEMM, block 128x128.
// MODE 2 (fc):   O1 = bf16(v) FL ; O2 = bf16(relu(v)) FL (chunk stride co)
// MODE 3 (mlp1): dxy[slice][row][0..3] partials of relu(v)*w2^T, slice = by*2+(w&1)
template <int MODE>
__global__ void __launch_bounds__(256, 2) gemm_fl2(
    const char* __restrict__ Afl, int ca,
    const char* __restrict__ Bfl, int nkg,
    const float* __restrict__ bias,
    char* __restrict__ O1, char* __restrict__ O2, int co,
    const float* __restrict__ w2, float* __restrict__ dxy)
{
  __shared__ char smem[16384];
  const int t = threadIdx.x, w = t >> 6, lane = t & 63;
  const int m0 = blockIdx.x * 128, n0 = blockIdx.y * 128;
  const int wm = (w >> 1) * 64, wn = (w & 1) * 64;

  const char* gsrc[4];
  char* ldst[4];
  #pragma unroll
  for (int s = 0; s < 4; ++s) {
    const int idx = w * 4 + s;
    if (idx < 8) gsrc[s] = Afl + (size_t)((m0 >> 4) + idx) * ca * 1024 + lane * 16;
    else         gsrc[s] = Bfl + (size_t)((n0 >> 4) + idx - 8) * nkg * 1024 + lane * 16;
    ldst[s] = smem + idx * 1024;
  }

  f32x4 acc[4][4];
  const f32x4 zero = {0.f, 0.f, 0.f, 0.f};
  #pragma unroll
  for (int i = 0; i < 4; ++i)
    #pragma unroll
    for (int j = 0; j < 4; ++j) acc[i][j] = zero;

  for (int kg = 0; kg < nkg; ++kg) {
    __syncthreads();
    #pragma unroll
    for (int s = 0; s < 4; ++s)
      gld_lds16(gsrc[s] + (size_t)kg * 1024, ldst[s]);
    __syncthreads();
    bf16x8 af[4], bv[4];
    #pragma unroll
    for (int i = 0; i < 4; ++i)
      af[i] = *(const bf16x8*)(smem + ((wm >> 4) + i) * 1024 + lane * 16);
    #pragma unroll
    for (int j = 0; j < 4; ++j)
      bv[j] = *(const bf16x8*)(smem + 8192 + ((wn >> 4) + j) * 1024 + lane * 16);
    #pragma unroll
    for (int i = 0; i < 4; ++i)
      #pragma unroll
      for (int j = 0; j < 4; ++j)
        acc[i][j] = __builtin_amdgcn_mfma_f32_16x16x32_bf16(af[i], bv[j], acc[i][j], 0, 0, 0);
  }

  const int lr = lane & 15, q4 = (lane >> 4) * 4;
  if (MODE == 2) {
    #pragma unroll
    for (int i = 0; i < 4; ++i) {
      #pragma unroll
      for (int j = 0; j < 4; ++j) {
        const int col = n0 + wn + j * 16 + lr;
        const float bvv = bias[col];
        #pragma unroll
        for (int r = 0; r < 4; ++r) {
          const int row = m0 + wm + i * 16 + q4 + r;
          const float v = acc[i][j][r] + bvv;
          *(__bf16*)(O1 + fl_off(row, col, co, 0)) = (__bf16)v;
          *(__bf16*)(O2 + fl_off(row, col, co, 0)) = (__bf16)fmaxf(v, 0.f);
        }
      }
    }
  } else {
    const int slice = blockIdx.y * 2 + (w & 1);
    #pragma unroll
    for (int i = 0; i < 4; ++i) {
      float v[4][4];   // [r][o]
      #pragma unroll
      for (int r = 0; r < 4; ++r)
        #pragma unroll
        for (int o = 0; o < 4; ++o) v[r][o] = 0.f;
      #pragma unroll
      for (int j = 0; j < 4; ++j) {
        const int col = n0 + wn + j * 16 + lr;
        const float bvv = bias[col];
        const float w20 = w2[col], w21 = w2[2048 + col], w22 = w2[4096 + col], w23 = w2[6144 + col];
        #pragma unroll
        for (int r = 0; r < 4; ++r) {
          const float pv = fmaxf(acc[i][j][r] + bvv, 0.f);
          v[r][0] += pv * w20; v[r][1] += pv * w21; v[r][2] += pv * w22; v[r][3] += pv * w23;
        }
      }
      #pragma unroll
      for (int m = 1; m <= 8; m <<= 1)
        #pragma unroll
        for (int r = 0; r < 4; ++r)
          #pragma unroll
          for (int o = 0; o < 4; ++o) v[r][o] += __shfl_xor(v[r][o], m);
      if (lr == 0) {
        #pragma unroll
        for (int r = 0; r < 4; ++r) {
          const int row = m0 + wm + i * 16 + q4 + r;
          float4 vv = make_float4(v[r][0], v[r][1], v[r][2], v[r][3]);
          *(float4*)(dxy + ((size_t)slice * Bsz + row) * 4) = vv;
        }
      }
    }
  }
}

// xy += sum(dxy slices) + b2; out[:,istep,:] = xy
__global__ void __launch_bounds__(256) finalize(
    const float* __restrict__ dxy, const float* __restrict__ b2,
    float* __restrict__ xy, float* __restrict__ out, int istep)
{
  const int b = blockIdx.x * 256 + threadIdx.x;
  float4 s = *(const float4*)b2;
  #pragma unroll 8
  for (int sl = 0; sl < 32; ++sl) {
    const float4 d = *(const float4*)(dxy + ((size_t)sl * Bsz + b) * 4);
    s.x += d.x; s.y += d.y; s.z += d.z; s.w += d.w;
  }
  float4 xv = *(const float4*)(xy + (size_t)b * 4);
  xv.x += s.x; xv.y += s.y; xv.z += s.z; xv.w += s.w;
  *(float4*)(xy + (size_t)b * 4) = xv;
  *(float4*)(out + (size_t)b * 20 + istep * 4) = xv;
}

extern "C" void kernel_launch(void* const* d_in, const int* in_sizes, int n_in,
                              void* d_out, int out_size, void* d_ws, size_t ws_size,
                              hipStream_t stream)
{
  const float* pv   = (const float*)d_in[0];
  const float* ptf  = (const float*)d_in[1];
  const float* w_ih = (const float*)d_in[2];
  const float* w_hh = (const float*)d_in[3];
  const float* b_ih = (const float*)d_in[4];
  const float* b_hh = (const float*)d_in[5];
  const float* w_fc = (const float*)d_in[6];
  const float* b_fc = (const float*)d_in[7];
  const float* w1   = (const float*)d_in[8];
  const float* b1   = (const float*)d_in[9];
  const float* w2   = (const float*)d_in[10];
  const float* b2   = (const float*)d_in[11];
  float* out = (float*)d_out;

  char* p = (char*)d_ws;
  auto carve = [&](size_t bytes) {
    char* r = p;
    p += (bytes + 255) & ~(size_t)255;
    return r;
  };
  char*  hxF   = carve((size_t)Bsz * 512 * 2);     // FL ca=16
  char*  hxrF  = carve((size_t)Bsz * 512 * 2);     // FL ca=16
  char*  hcatF = carve((size_t)Bsz * 1024 * 2);    // FL ca=32: h1 kg 0..15, h2 kg 16..31
  float* dxy   = (float*)carve((size_t)32 * Bsz * 4 * 4);
  float* xy    = (float*)carve((size_t)Bsz * 4 * 4);
  char*  whhF  = carve((size_t)1536 * 512 * 2);    // FL nkg=16
  char*  wfcF  = carve((size_t)512 * 1024 * 2);    // FL nkg=32
  char*  w1F   = carve((size_t)2048 * 512 * 2);    // FL nkg=16

  pack_fl<<<(1536 * 512 / 8 + 255) / 256, 256, 0, stream>>>(w_hh, whhF, 512, 4, 1536 * 512 / 8);
  pack_fl<<<(512 * 1024 / 8 + 255) / 256, 256, 0, stream>>>(w_fc, wfcF, 1024, 5, 512 * 1024 / 8);
  pack_fl<<<(2048 * 512 / 8 + 255) / 256, 256, 0, stream>>>(w1, w1F, 512, 4, 2048 * 512 / 8);
  pack_fl<<<(Bsz * 512 / 8 + 255) / 256, 256, 0, stream>>>(ptf, hxF, 512, 4, Bsz * 512 / 8);
  hipMemsetAsync(xy, 0, (size_t)Bsz * 4 * 4, stream);

  for (int i = 0; i < HORsz; ++i) {
    // h1 = GRUCell(xy, hx) -> hcat kg 0..15
    gru_fused2<<<dim3(8, Bsz / 128), 256, 0, stream>>>(
        hxF, 16, whhF, xy, 4, w_ih, b_ih, b_hh, hcatF, 32, 0);
    // h2 = GRUCell(pv[:,i], h1) -> hcat kg 16..31
    gru_fused2<<<dim3(8, Bsz / 128), 256, 0, stream>>>(
        hcatF, 32, whhF, pv + i * 4, HORsz * 4, w_ih, b_ih, b_hh, hcatF, 32, 16);
    // hx = hcat @ w_fc^T + b_fc ; hxr = relu(hx) (both FL)
    gemm_fl2<2><<<dim3(Bsz / 128, 4), 256, 0, stream>>>(
        hcatF, 32, wfcF, 32, b_fc, hxF, hxrF, 16, nullptr, nullptr);
    // dxy partials = relu(relu-gemm) @ w2^T  (mlp1+mlp2 fused)
    gemm_fl2<3><<<dim3(Bsz / 128, 16), 256, 0, stream>>>(
        hxrF, 16, w1F, 16, b1, nullptr, nullptr, 0, w2, dxy);
    // xy += sum + b2; out
    finalize<<<Bsz / 256, 256, 0, stream>>>(dxy, b2, xy, out, i);
  }
}

// Round 5
// 1091.326 us; speedup vs baseline: 1.3953x; 1.0378x over previous
//
#include <hip/hip_runtime.h>
#include <hip/hip_bf16.h>
#include <cstdint>
#include <cstddef>

#define Bsz 16384
#define HORsz 5

using bf16_t = __hip_bfloat16;
typedef __bf16 bf16x8 __attribute__((ext_vector_type(8)));
typedef float f32x4 __attribute__((ext_vector_type(4)));

__device__ __forceinline__ void gld_lds16(const void* g, void* l) {
  __builtin_amdgcn_global_load_lds((__attribute__((address_space(1))) void*)g,
                                   (__attribute__((address_space(3))) void*)l,
                                   16, 0, 0);
}

__device__ __forceinline__ float sigm(float x) { return 1.f / (1.f + __expf(-x)); }
__device__ __forceinline__ float tanh_fast(float x) {
  x = fminf(fmaxf(x, -20.f), 20.f);
  float e = __expf(2.f * x);
  return (e - 1.f) / (e + 1.f);
}

// XCD-aware swizzle: blocks b, b+8, b+16 ... (same XCD under b%8 round-robin)
// sweep all n-tiles of one m-tile consecutively. Requires NB_M % 8 == 0.
__device__ __forceinline__ void swz(int b, int nbn, int& n, int& m) {
  const int x = b & 7;
  const int k = b >> 3;
  n = k % nbn;
  m = x + 8 * (k / nbn);
}

// Fragment layout (FL) bf16 [R,C]: 1KB chunk = 16 rows x 32 cols; lane l <-> bytes [16l,16l+16).
// chunk(rg,kg) at ((rg*ca)+cofs+kg)*1024 ; within: (((col>>3)&3)*16 + (row&15))*16 + (col&7)*2
__device__ __forceinline__ size_t fl_off(int row, int col, int ca, int cofs) {
  return (size_t)((row >> 4) * ca + cofs + (col >> 5)) * 1024
       + (size_t)((((col >> 3) & 3) * 16 + (row & 15)) * 16 + (col & 7) * 2);
}

// fp32 row-major [R,C] -> bf16 FL.
__global__ void __launch_bounds__(256) pack_fl(const float* __restrict__ src,
                                               char* __restrict__ dst,
                                               int C, int cs, int npieces) {
  const int p = blockIdx.x * 256 + threadIdx.x;
  if (p >= npieces) return;
  const int chunk = p >> 6, wi = p & 63;
  const int colgrp = wi >> 4, r15 = wi & 15;
  const int rowgrp = chunk >> cs, kg = chunk & ((1 << cs) - 1);
  const int row = rowgrp * 16 + r15;
  const int col = kg * 32 + colgrp * 8;
  const float* s = src + (size_t)row * C + col;
  bf16x8 v;
  #pragma unroll
  for (int j = 0; j < 8; ++j) v[j] = (__bf16)s[j];
  *(bf16x8*)(dst + (size_t)p * 16) = v;
}

// Fused GRU cell, LDS-staged. Block: 128 rows x 64 chans x 3 gates. K=512 (16 kg).
// Wave: 64 rows x 32 chans x 3 gates. LDS: A 8 chunks + B 12 chunks per kg.
__global__ void __launch_bounds__(256, 2) gru_fused2(
    const char* __restrict__ Afl, int ca,   // A = hprev FL, K chunks 0..15
    const char* __restrict__ Wfl,           // whh FL [1536,512], nkg=16
    const float* __restrict__ x, int ldx,   // fp32, 4 cols used
    const float* __restrict__ w_ih, const float* __restrict__ b_ih,
    const float* __restrict__ b_hh,
    char* __restrict__ Ofl, int co, int kofs)
{
  __shared__ char smem[20480];
  const int t = threadIdx.x, w = t >> 6, lane = t & 63;
  int bn, bm;
  swz(blockIdx.x, 8, bn, bm);
  const int m0 = bm * 128;
  const int n0 = bn * 64;
  const int wm = (w >> 1) * 64, wc = (w & 1) * 32;

  // staging: 20 chunks/kg; wave w stages idx = w*5+s
  const char* gsrc[5];
  char* ldst[5];
  #pragma unroll
  for (int s = 0; s < 5; ++s) {
    const int idx = w * 5 + s;
    if (idx < 8) {
      gsrc[s] = Afl + (size_t)((m0 >> 4) + idx) * ca * 1024 + lane * 16;
    } else {
      const int c = idx - 8, g = c >> 2, cr = c & 3;
      gsrc[s] = Wfl + (size_t)(g * 32 + (n0 >> 4) + cr) * 16 * 1024 + lane * 16;
    }
    ldst[s] = smem + idx * 1024;
  }

  f32x4 acc[3][4][2];
  const f32x4 zero = {0.f, 0.f, 0.f, 0.f};
  #pragma unroll
  for (int g = 0; g < 3; ++g)
    #pragma unroll
    for (int i = 0; i < 4; ++i)
      #pragma unroll
      for (int jt = 0; jt < 2; ++jt) acc[g][i][jt] = zero;

  for (int kg = 0; kg < 16; ++kg) {
    __syncthreads();
    #pragma unroll
    for (int s = 0; s < 5; ++s)
      gld_lds16(gsrc[s] + (size_t)kg * 1024, ldst[s]);
    __syncthreads();
    bf16x8 af[4];
    #pragma unroll
    for (int i = 0; i < 4; ++i)
      af[i] = *(const bf16x8*)(smem + ((wm >> 4) + i) * 1024 + lane * 16);
    #pragma unroll
    for (int g = 0; g < 3; ++g)
      #pragma unroll
      for (int jt = 0; jt < 2; ++jt) {
        const bf16x8 bv = *(const bf16x8*)(smem + 8192 + (g * 4 + (w & 1) * 2 + jt) * 1024 + lane * 16);
        #pragma unroll
        for (int i = 0; i < 4; ++i)
          acc[g][i][jt] = __builtin_amdgcn_mfma_f32_16x16x32_bf16(af[i], bv, acc[g][i][jt], 0, 0, 0);
      }
  }

  const int lr = lane & 15, q4 = (lane >> 4) * 4;
  __syncthreads();                 // staged data no longer needed; reuse smem
  char* rep = smem + w * 4096;     // wave-private repack slice (4 chunks)
  #pragma unroll
  for (int jt = 0; jt < 2; ++jt) {
    const int c = n0 + wc + jt * 16 + lr;
    const float4 wr  = *(const float4*)(w_ih + (size_t)c * 4);
    const float4 wz  = *(const float4*)(w_ih + (size_t)(c + 512) * 4);
    const float4 wnn = *(const float4*)(w_ih + (size_t)(c + 1024) * 4);
    const float bir = b_ih[c], biz = b_ih[c + 512], bin = b_ih[c + 1024];
    const float bhr = b_hh[c], bhz = b_hh[c + 512], bhn = b_hh[c + 1024];
    const int wbase = ((jt * 2 + (lr >> 3)) * 16 + q4) * 16 + (lr & 7) * 2;
    #pragma unroll
    for (int i = 0; i < 4; ++i) {
      #pragma unroll
      for (int r4 = 0; r4 < 4; ++r4) {
        const int row = m0 + wm + i * 16 + q4 + r4;
        const float4 xv = *(const float4*)(x + (size_t)row * ldx);
        const float gir = bir + xv.x * wr.x  + xv.y * wr.y  + xv.z * wr.z  + xv.w * wr.w;
        const float giz = biz + xv.x * wz.x  + xv.y * wz.y  + xv.z * wz.z  + xv.w * wz.w;
        const float gin = bin + xv.x * wnn.x + xv.y * wnn.y + xv.z * wnn.z + xv.w * wnn.w;
        const float rr = sigm(gir + acc[0][i][jt][r4] + bhr);
        const float zz = sigm(giz + acc[1][i][jt][r4] + bhz);
        const float nn = tanh_fast(gin + rr * (acc[2][i][jt][r4] + bhn));
        const float hp = (float)*(const __bf16*)(Afl + fl_off(row, c, ca, 0));
        *(__bf16*)(rep + i * 1024 + wbase + r4 * 16) = (__bf16)((1.f - zz) * nn + zz * hp);
      }
    }
  }
  __syncthreads();                 // drain LDS writes before readback
  const int rg0 = (m0 >> 4) + (wm >> 4);
  const int cg = kofs + (n0 >> 5) + (w & 1);
  #pragma unroll
  for (int i = 0; i < 4; ++i) {
    const bf16x8 v = *(const bf16x8*)(rep + i * 1024 + lane * 16);
    *(bf16x8*)(Ofl + ((size_t)(rg0 + i) * co + cg) * 1024 + lane * 16) = v;
  }
}

// Generic LDS-staged FL GEMM, block 128x128, XCD-swizzled.
// MODE 2 (fc):   O1 = bf16(v) FL ; O2 = bf16(relu(v)) FL — coalesced via LDS repack
// MODE 3 (mlp1): dxy[slice][row][0..3] partials of relu(v)*w2^T, slice = bn*2+(w&1)
template <int MODE>
__global__ void __launch_bounds__(256, 2) gemm_fl2(
    const char* __restrict__ Afl, int ca,
    const char* __restrict__ Bfl, int nkg, int nbn,
    const float* __restrict__ bias,
    char* __restrict__ O1, char* __restrict__ O2, int co,
    const float* __restrict__ w2, float* __restrict__ dxy)
{
  __shared__ char smem[16384];
  const int t = threadIdx.x, w = t >> 6, lane = t & 63;
  int bn, bm;
  swz(blockIdx.x, nbn, bn, bm);
  const int m0 = bm * 128, n0 = bn * 128;
  const int wm = (w >> 1) * 64, wn = (w & 1) * 64;

  const char* gsrc[4];
  char* ldst[4];
  #pragma unroll
  for (int s = 0; s < 4; ++s) {
    const int idx = w * 4 + s;
    if (idx < 8) gsrc[s] = Afl + (size_t)((m0 >> 4) + idx) * ca * 1024 + lane * 16;
    else         gsrc[s] = Bfl + (size_t)((n0 >> 4) + idx - 8) * nkg * 1024 + lane * 16;
    ldst[s] = smem + idx * 1024;
  }

  f32x4 acc[4][4];
  const f32x4 zero = {0.f, 0.f, 0.f, 0.f};
  #pragma unroll
  for (int i = 0; i < 4; ++i)
    #pragma unroll
    for (int j = 0; j < 4; ++j) acc[i][j] = zero;

  for (int kg = 0; kg < nkg; ++kg) {
    __syncthreads();
    #pragma unroll
    for (int s = 0; s < 4; ++s)
      gld_lds16(gsrc[s] + (size_t)kg * 1024, ldst[s]);
    __syncthreads();
    bf16x8 af[4], bv[4];
    #pragma unroll
    for (int i = 0; i < 4; ++i)
      af[i] = *(const bf16x8*)(smem + ((wm >> 4) + i) * 1024 + lane * 16);
    #pragma unroll
    for (int j = 0; j < 4; ++j)
      bv[j] = *(const bf16x8*)(smem + 8192 + ((wn >> 4) + j) * 1024 + lane * 16);
    #pragma unroll
    for (int i = 0; i < 4; ++i)
      #pragma unroll
      for (int j = 0; j < 4; ++j)
        acc[i][j] = __builtin_amdgcn_mfma_f32_16x16x32_bf16(af[i], bv[j], acc[i][j], 0, 0, 0);
  }

  const int lr = lane & 15, q4 = (lane >> 4) * 4;
  if (MODE == 2) {
    __syncthreads();               // reuse smem for repack
    char* rep = smem + w * 2048;   // wave-private, 2 chunks, reused per i
    const int rgb = (m0 >> 4) + (wm >> 4);
    const int cgb = (n0 >> 5) + (wn >> 5);
    for (int i = 0; i < 4; ++i) {
      #pragma unroll
      for (int j = 0; j < 4; ++j) {
        const int col = n0 + wn + j * 16 + lr;
        const float bvv = bias[col];
        const int wbase = (((j & 1) * 2 + (lr >> 3)) * 16 + q4) * 16 + (lr & 7) * 2;
        #pragma unroll
        for (int r = 0; r < 4; ++r) {
          const float v = acc[i][j][r] + bvv;
          *(__bf16*)(rep + (j >> 1) * 1024 + wbase + r * 16) = (__bf16)v;
        }
      }
      __syncthreads();             // order writes before readback (and across i reuse)
      #pragma unroll
      for (int jc = 0; jc < 2; ++jc) {
        const bf16x8 v = *(const bf16x8*)(rep + jc * 1024 + lane * 16);
        const size_t cb = ((size_t)(rgb + i) * co + cgb + jc) * 1024 + lane * 16;
        *(bf16x8*)(O1 + cb) = v;
        bf16x8 vr;
        #pragma unroll
        for (int e = 0; e < 8; ++e) vr[e] = (__bf16)fmaxf((float)v[e], 0.f);
        *(bf16x8*)(O2 + cb) = vr;
      }
      __syncthreads();
    }
  } else {
    const int slice = bn * 2 + (w & 1);
    #pragma unroll
    for (int i = 0; i < 4; ++i) {
      float v[4][4];   // [r][o]
      #pragma unroll
      for (int r = 0; r < 4; ++r)
        #pragma unroll
        for (int o = 0; o < 4; ++o) v[r][o] = 0.f;
      #pragma unroll
      for (int j = 0; j < 4; ++j) {
        const int col = n0 + wn + j * 16 + lr;
        const float bvv = bias[col];
        const float w20 = w2[col], w21 = w2[2048 + col], w22 = w2[4096 + col], w23 = w2[6144 + col];
        #pragma unroll
        for (int r = 0; r < 4; ++r) {
          const float pv = fmaxf(acc[i][j][r] + bvv, 0.f);
          v[r][0] += pv * w20; v[r][1] += pv * w21; v[r][2] += pv * w22; v[r][3] += pv * w23;
        }
      }
      #pragma unroll
      for (int m = 1; m <= 8; m <<= 1)
        #pragma unroll
        for (int r = 0; r < 4; ++r)
          #pragma unroll
          for (int o = 0; o < 4; ++o) v[r][o] += __shfl_xor(v[r][o], m);
      if (lr == 0) {
        #pragma unroll
        for (int r = 0; r < 4; ++r) {
          const int row = m0 + wm + i * 16 + q4 + r;
          float4 vv = make_float4(v[r][0], v[r][1], v[r][2], v[r][3]);
          *(float4*)(dxy + ((size_t)slice * Bsz + row) * 4) = vv;
        }
      }
    }
  }
}

// xy += sum(dxy slices) + b2; out[:,istep,:] = xy
__global__ void __launch_bounds__(256) finalize(
    const float* __restrict__ dxy, const float* __restrict__ b2,
    float* __restrict__ xy, float* __restrict__ out, int istep)
{
  const int b = blockIdx.x * 256 + threadIdx.x;
  float4 s = *(const float4*)b2;
  #pragma unroll 8
  for (int sl = 0; sl < 32; ++sl) {
    const float4 d = *(const float4*)(dxy + ((size_t)sl * Bsz + b) * 4);
    s.x += d.x; s.y += d.y; s.z += d.z; s.w += d.w;
  }
  float4 xv = *(const float4*)(xy + (size_t)b * 4);
  xv.x += s.x; xv.y += s.y; xv.z += s.z; xv.w += s.w;
  *(float4*)(xy + (size_t)b * 4) = xv;
  *(float4*)(out + (size_t)b * 20 + istep * 4) = xv;
}

extern "C" void kernel_launch(void* const* d_in, const int* in_sizes, int n_in,
                              void* d_out, int out_size, void* d_ws, size_t ws_size,
                              hipStream_t stream)
{
  const float* pv   = (const float*)d_in[0];
  const float* ptf  = (const float*)d_in[1];
  const float* w_ih = (const float*)d_in[2];
  const float* w_hh = (const float*)d_in[3];
  const float* b_ih = (const float*)d_in[4];
  const float* b_hh = (const float*)d_in[5];
  const float* w_fc = (const float*)d_in[6];
  const float* b_fc = (const float*)d_in[7];
  const float* w1   = (const float*)d_in[8];
  const float* b1   = (const float*)d_in[9];
  const float* w2   = (const float*)d_in[10];
  const float* b2   = (const float*)d_in[11];
  float* out = (float*)d_out;

  char* p = (char*)d_ws;
  auto carve = [&](size_t bytes) {
    char* r = p;
    p += (bytes + 255) & ~(size_t)255;
    return r;
  };
  char*  hxF   = carve((size_t)Bsz * 512 * 2);     // FL ca=16
  char*  hxrF  = carve((size_t)Bsz * 512 * 2);     // FL ca=16
  char*  hcatF = carve((size_t)Bsz * 1024 * 2);    // FL ca=32: h1 kg 0..15, h2 kg 16..31
  float* dxy   = (float*)carve((size_t)32 * Bsz * 4 * 4);
  float* xy    = (float*)carve((size_t)Bsz * 4 * 4);
  char*  whhF  = carve((size_t)1536 * 512 * 2);    // FL nkg=16
  char*  wfcF  = carve((size_t)512 * 1024 * 2);    // FL nkg=32
  char*  w1F   = carve((size_t)2048 * 512 * 2);    // FL nkg=16

  pack_fl<<<(1536 * 512 / 8 + 255) / 256, 256, 0, stream>>>(w_hh, whhF, 512, 4, 1536 * 512 / 8);
  pack_fl<<<(512 * 1024 / 8 + 255) / 256, 256, 0, stream>>>(w_fc, wfcF, 1024, 5, 512 * 1024 / 8);
  pack_fl<<<(2048 * 512 / 8 + 255) / 256, 256, 0, stream>>>(w1, w1F, 512, 4, 2048 * 512 / 8);
  pack_fl<<<(Bsz * 512 / 8 + 255) / 256, 256, 0, stream>>>(ptf, hxF, 512, 4, Bsz * 512 / 8);
  hipMemsetAsync(xy, 0, (size_t)Bsz * 4 * 4, stream);

  for (int i = 0; i < HORsz; ++i) {
    // h1 = GRUCell(xy, hx) -> hcat kg 0..15
    gru_fused2<<<1024, 256, 0, stream>>>(
        hxF, 16, whhF, xy, 4, w_ih, b_ih, b_hh, hcatF, 32, 0);
    // h2 = GRUCell(pv[:,i], h1) -> hcat kg 16..31
    gru_fused2<<<1024, 256, 0, stream>>>(
        hcatF, 32, whhF, pv + i * 4, HORsz * 4, w_ih, b_ih, b_hh, hcatF, 32, 16);
    // hx = hcat @ w_fc^T + b_fc ; hxr = relu(hx) (both FL, coalesced stores)
    gemm_fl2<2><<<512, 256, 0, stream>>>(
        hcatF, 32, wfcF, 32, 4, b_fc, hxF, hxrF, 16, nullptr, nullptr);
    // dxy partials = relu(relu-gemm) @ w2^T  (mlp1+mlp2 fused)
    gemm_fl2<3><<<2048, 256, 0, stream>>>(
        hxrF, 16, w1F, 16, 16, b1, nullptr, nullptr, 0, w2, dxy);
    // xy += sum + b2; out
    finalize<<<Bsz / 256, 256, 0, stream>>>(dxy, b2, xy, out, i);
  }
}